// Round 4
// baseline (146.428 us; speedup 1.0000x reference)
//
#include <hip/hip_runtime.h>
#include <math.h>

#define NSUB   2048
#define NTRIAL 40
#define NPATH  12341
#define PBLK   1024
#define NFULL  (NPATH / PBLK)          // 12 full iterations (12288 paths)
#define NTAIL  (NPATH - NFULL * PBLK)  // 53 remainder paths

// ---------------------------------------------------------------------------
// Kernel 1: analytic per-path decode — NO read of the paths array.
// Paths are the lex-ordered monotone sequences 0^a 1^b 2^c 3^d (a+b+c+d=40),
// ordered by a desc, then b desc, then c desc (verified against the
// reference's enumeration recurrence). Unrank p -> (a,b,c,d):
//   a: groups of size C(m+2,2), m = 40-a, scanned a=40..0
//   b: groups of size (m-b+1),   scanned b=m..0
//   c = (m-b) - r, d = r
// logp = prior[first run] + sum over runs [(len-1)*lT[s][s]] + boundaries.
// Record: int2 { float logp (bitcast), t1 | t2<<6 | t3<<12 }.
// ---------------------------------------------------------------------------
__global__ __launch_bounds__(256) void path_kernel(
        const float* __restrict__ w_sp,
        const float* __restrict__ w_tr,
        int2* __restrict__ rec) {
    __shared__ float sprior[4];
    __shared__ float str[16];
    const int tid = threadIdx.x;

    if (tid < 4) {
        float m = fmaxf(fmaxf(w_sp[0], w_sp[1]), fmaxf(w_sp[2], w_sp[3]));
        float s = 0.f;
        for (int k = 0; k < 4; k++) s += __expf(w_sp[k] - m);
        sprior[tid] = w_sp[tid] - (__logf(s) + m);
    } else if (tid < 20) {
        int idx = tid - 4, i = idx >> 2, j = idx & 3;
        float m = -1e30f;
        for (int k = i; k < 4; k++) m = fmaxf(m, w_tr[i*4 + k]);
        float s = 0.f;
        for (int k = i; k < 4; k++) s += __expf(w_tr[i*4 + k] - m);
        str[idx] = (j >= i) ? (w_tr[i*4 + j] - (__logf(s) + m)) : 0.f;
    }
    __syncthreads();

    int p = blockIdx.x * 256 + tid;
    if (p >= NPATH) return;

    int r = p, a = 0;
    for (int aa = NTRIAL; aa >= 0; aa--) {
        int m = NTRIAL - aa;
        int cnt = ((m + 1) * (m + 2)) >> 1;
        if (r < cnt) { a = aa; break; }
        r -= cnt;
    }
    const int m = NTRIAL - a;
    int b = 0;
    for (int bb = m; bb >= 0; bb--) {
        int cnt = m - bb + 1;
        if (r < cnt) { b = bb; break; }
        r -= cnt;
    }
    const int c = (m - b) - r;
    const int d = r;

    const int lens[4] = {a, b, c, d};
    float lp = 0.f;
    int prev = -1;
#pragma unroll
    for (int s = 0; s < 4; s++) {
        int L = lens[s];
        if (L > 0) {
            lp += (prev < 0) ? sprior[s] : str[prev*4 + s];
            lp += (float)(L - 1) * str[s*4 + s];
            prev = s;
        }
    }
    const int t1 = a, t2 = a + b, t3 = a + b + c;
    rec[p] = make_int2(__float_as_int(lp), t1 | (t2 << 6) | (t3 << 12));
}

// ---------------------------------------------------------------------------
// Kernel 2: one block (1024 thr) per subject.
// rec loads issued BEFORE the prologue (independent of it) so L2 latency
// hides behind the prefix-sum build. numerator = exp(logp + D1+D2+D3).
// Output written with non-temporal dword stores (write-once data).
// ---------------------------------------------------------------------------
__global__ __launch_bounds__(1024) void post_kernel(
        const int* __restrict__ resp,
        const float* __restrict__ w_ss,
        const int2* __restrict__ rec,
        float* __restrict__ out) {
    __shared__ float lsr[16];               // log p_state_responses
    __shared__ int   rs[NTRIAL];
    __shared__ float V[4][NTRIAL];          // V[k][t] = lsr[k][rs[t]]
    __shared__ float C[4][NTRIAL + 1];
    __shared__ float D1[NTRIAL + 1], D2[NTRIAL + 1], D3[NTRIAL + 1];
    __shared__ float red[16];
    __shared__ float s_inv;

    const int s = blockIdx.x;
    const int tid = threadIdx.x;

    // ---- issue all rec loads up front (independent of prologue) ----
    int2 r[NFULL];
#pragma unroll
    for (int i = 0; i < NFULL; i++) r[i] = rec[tid + PBLK * i];
    const bool tail = (tid < NTAIL);
    int2 rt = tail ? rec[NFULL * PBLK + tid] : make_int2(0, 0);

    // ---- prologue: lsr + responses ----
    if (tid < 16) {
        const float psr[4][4] = {
            {3.f/9.f, 4.f/9.f, 1.f/9.f, 1.f/9.f},
            {0.f,     4.f/6.f, 1.f/6.f, 1.f/6.f},
            {0.f,     0.f,     0.5f,    0.5f},
            {0.f,     0.f,     0.f,     1.f}};
        int i = tid >> 2, rr = tid & 3;
        float mx = -1e30f;
        for (int j = 0; j <= i; j++) mx = fmaxf(mx, w_ss[i*4 + j]);
        float e[4] = {0.f,0.f,0.f,0.f}, ssum = 0.f;
        for (int j = 0; j <= i; j++) { e[j] = __expf(w_ss[i*4 + j] - mx); ssum += e[j]; }
        float acc = 0.f;
        for (int j = 0; j <= i; j++) acc += (e[j] / ssum) * psr[j][rr];
        lsr[tid] = __logf(acc);
    }
    if (tid < NTRIAL) rs[tid] = resp[(size_t)s * NTRIAL + tid];
    __syncthreads();

    // gather step in parallel (160 threads), scan chain by 4 threads
    if (tid < 4 * NTRIAL) {
        int k = tid / NTRIAL, t = tid - k * NTRIAL;
        V[k][t] = lsr[k*4 + rs[t]];
    }
    __syncthreads();
    if (tid < 4) {
        float c = 0.f;
        C[tid][0] = 0.f;
        for (int t = 0; t < NTRIAL; t++) {
            c += V[tid][t];
            C[tid][t+1] = c;
        }
    }
    __syncthreads();
    if (tid <= NTRIAL) {
        float ct3 = C[3][NTRIAL];
        D1[tid] = C[0][tid] - C[1][tid];
        D2[tid] = C[1][tid] - C[2][tid];
        D3[tid] = C[2][tid] - C[3][tid] + ct3;
    }
    __syncthreads();

    // ---- main: 12 guard-free elements + tail ----
    float nums[NFULL];
    float lsum = 0.f;
#pragma unroll
    for (int i = 0; i < NFULL; i++) {
        int b = r[i].y;
        int t1 = b & 63, t2 = (b >> 6) & 63, t3 = (b >> 12) & 63;
        float v = __expf(__int_as_float(r[i].x) + D1[t1] + D2[t2] + D3[t3]);
        nums[i] = v;
        lsum += v;
    }
    float numt = 0.f;
    if (tail) {
        int b = rt.y;
        int t1 = b & 63, t2 = (b >> 6) & 63, t3 = (b >> 12) & 63;
        numt = __expf(__int_as_float(rt.x) + D1[t1] + D2[t2] + D3[t3]);
        lsum += numt;
    }

    for (int off = 32; off > 0; off >>= 1)
        lsum += __shfl_down(lsum, off, 64);
    const int wave = tid >> 6, lane = tid & 63;
    if (lane == 0) red[wave] = lsum;
    __syncthreads();
    if (tid == 0) {
        float t = 0.f;
        for (int w = 0; w < 16; w++) t += red[w];
        s_inv = 1.f / t;
    }
    __syncthreads();
    const float inv = s_inv;

    float* orow = out + (size_t)s * NPATH;
#pragma unroll
    for (int i = 0; i < NFULL; i++)
        __builtin_nontemporal_store(nums[i] * inv, &orow[tid + PBLK * i]);
    if (tail)
        __builtin_nontemporal_store(numt * inv, &orow[NFULL * PBLK + tid]);
}

// ---------------------------------------------------------------------------
extern "C" void kernel_launch(void* const* d_in, const int* in_sizes, int n_in,
                              void* d_out, int out_size, void* d_ws, size_t ws_size,
                              hipStream_t stream) {
    const int*   resp  = (const int*)d_in[0];
    // d_in[1] (paths) intentionally unused: decoded analytically from index.
    const float* w_ss  = (const float*)d_in[2];
    const float* w_sp  = (const float*)d_in[3];
    const float* w_tr  = (const float*)d_in[4];
    float* out = (float*)d_out;

    int2* rec = (int2*)d_ws;   // NPATH records (8 B each)

    path_kernel<<<(NPATH + 255) / 256, 256, 0, stream>>>(w_sp, w_tr, rec);
    post_kernel<<<NSUB, PBLK, 0, stream>>>(resp, w_ss, rec, out);
}

// Round 5
// 139.991 us; speedup vs baseline: 1.0460x; 1.0460x over previous
//
#include <hip/hip_runtime.h>
#include <math.h>

#define NSUB   2048
#define NTRIAL 40
#define NPATH  12341
#define PBLK   1024
#define NFULL  (NPATH / PBLK)          // 12 full iterations (12288 paths)
#define NTAIL  (NPATH - NFULL * PBLK)  // 53 remainder paths

// ---------------------------------------------------------------------------
// Kernel 1: analytic per-path decode — NO read of the paths array.
// Paths are the lex-ordered monotone sequences 0^a 1^b 2^c 3^d (a+b+c+d=40).
// Unrank p -> (a,b,c,d); logp via run-length closed form.
// Record: int2 { float logp (bitcast), t1 | t2<<6 | t3<<12 }.
// ---------------------------------------------------------------------------
__global__ __launch_bounds__(256) void path_kernel(
        const float* __restrict__ w_sp,
        const float* __restrict__ w_tr,
        int2* __restrict__ rec) {
    __shared__ float sprior[4];
    __shared__ float str[16];
    const int tid = threadIdx.x;

    if (tid < 4) {
        float m = fmaxf(fmaxf(w_sp[0], w_sp[1]), fmaxf(w_sp[2], w_sp[3]));
        float s = 0.f;
        for (int k = 0; k < 4; k++) s += __expf(w_sp[k] - m);
        sprior[tid] = w_sp[tid] - (__logf(s) + m);
    } else if (tid < 20) {
        int idx = tid - 4, i = idx >> 2, j = idx & 3;
        float m = -1e30f;
        for (int k = i; k < 4; k++) m = fmaxf(m, w_tr[i*4 + k]);
        float s = 0.f;
        for (int k = i; k < 4; k++) s += __expf(w_tr[i*4 + k] - m);
        str[idx] = (j >= i) ? (w_tr[i*4 + j] - (__logf(s) + m)) : 0.f;
    }
    __syncthreads();

    int p = blockIdx.x * 256 + tid;
    if (p >= NPATH) return;

    int r = p, a = 0;
    for (int aa = NTRIAL; aa >= 0; aa--) {
        int m = NTRIAL - aa;
        int cnt = ((m + 1) * (m + 2)) >> 1;
        if (r < cnt) { a = aa; break; }
        r -= cnt;
    }
    const int m = NTRIAL - a;
    int b = 0;
    for (int bb = m; bb >= 0; bb--) {
        int cnt = m - bb + 1;
        if (r < cnt) { b = bb; break; }
        r -= cnt;
    }
    const int c = (m - b) - r;
    const int d = r;

    const int lens[4] = {a, b, c, d};
    float lp = 0.f;
    int prev = -1;
#pragma unroll
    for (int s = 0; s < 4; s++) {
        int L = lens[s];
        if (L > 0) {
            lp += (prev < 0) ? sprior[s] : str[prev*4 + s];
            lp += (float)(L - 1) * str[s*4 + s];
            prev = s;
        }
    }
    const int t1 = a, t2 = a + b, t3 = a + b + c;
    rec[p] = make_int2(__float_as_int(lp), t1 | (t2 << 6) | (t3 << 12));
}

// ---------------------------------------------------------------------------
// Kernel 2: one block (1024 thr) per subject.
// rec loads issued BEFORE the prologue so L2 latency hides behind the
// prefix-sum build. numerator = exp(logp + D1[t1] + D2[t2] + D3[t3]),
// with CT3 folded into D3. Plain (write-back) stores — fills prove they
// reach 6.5 TB/s; non-temporal measured as a slight regression.
// ---------------------------------------------------------------------------
__global__ __launch_bounds__(1024) void post_kernel(
        const int* __restrict__ resp,
        const float* __restrict__ w_ss,
        const int2* __restrict__ rec,
        float* __restrict__ out) {
    __shared__ float lsr[16];               // log p_state_responses
    __shared__ int   rs[NTRIAL];
    __shared__ float V[4][NTRIAL];          // V[k][t] = lsr[k][rs[t]]
    __shared__ float C[4][NTRIAL + 1];
    __shared__ float D1[NTRIAL + 1], D2[NTRIAL + 1], D3[NTRIAL + 1];
    __shared__ float red[16];
    __shared__ float s_inv;

    const int s = blockIdx.x;
    const int tid = threadIdx.x;

    // ---- issue all rec loads up front (independent of prologue) ----
    int2 r[NFULL];
#pragma unroll
    for (int i = 0; i < NFULL; i++) r[i] = rec[tid + PBLK * i];
    const bool tail = (tid < NTAIL);
    int2 rt = tail ? rec[NFULL * PBLK + tid] : make_int2(0, 0);

    // ---- prologue: lsr + responses ----
    if (tid < 16) {
        const float psr[4][4] = {
            {3.f/9.f, 4.f/9.f, 1.f/9.f, 1.f/9.f},
            {0.f,     4.f/6.f, 1.f/6.f, 1.f/6.f},
            {0.f,     0.f,     0.5f,    0.5f},
            {0.f,     0.f,     0.f,     1.f}};
        int i = tid >> 2, rr = tid & 3;
        float mx = -1e30f;
        for (int j = 0; j <= i; j++) mx = fmaxf(mx, w_ss[i*4 + j]);
        float e[4] = {0.f,0.f,0.f,0.f}, ssum = 0.f;
        for (int j = 0; j <= i; j++) { e[j] = __expf(w_ss[i*4 + j] - mx); ssum += e[j]; }
        float acc = 0.f;
        for (int j = 0; j <= i; j++) acc += (e[j] / ssum) * psr[j][rr];
        lsr[tid] = __logf(acc);
    }
    if (tid < NTRIAL) rs[tid] = resp[(size_t)s * NTRIAL + tid];
    __syncthreads();

    // gather step in parallel (160 threads), scan chain by 4 threads
    if (tid < 4 * NTRIAL) {
        int k = tid / NTRIAL, t = tid - k * NTRIAL;
        V[k][t] = lsr[k*4 + rs[t]];
    }
    __syncthreads();
    if (tid < 4) {
        float c = 0.f;
        C[tid][0] = 0.f;
        for (int t = 0; t < NTRIAL; t++) {
            c += V[tid][t];
            C[tid][t+1] = c;
        }
    }
    __syncthreads();
    if (tid <= NTRIAL) {
        float ct3 = C[3][NTRIAL];
        D1[tid] = C[0][tid] - C[1][tid];
        D2[tid] = C[1][tid] - C[2][tid];
        D3[tid] = C[2][tid] - C[3][tid] + ct3;
    }
    __syncthreads();

    // ---- main: 12 guard-free elements + tail ----
    float nums[NFULL];
    float lsum = 0.f;
#pragma unroll
    for (int i = 0; i < NFULL; i++) {
        int b = r[i].y;
        int t1 = b & 63, t2 = (b >> 6) & 63, t3 = (b >> 12) & 63;
        float v = __expf(__int_as_float(r[i].x) + D1[t1] + D2[t2] + D3[t3]);
        nums[i] = v;
        lsum += v;
    }
    float numt = 0.f;
    if (tail) {
        int b = rt.y;
        int t1 = b & 63, t2 = (b >> 6) & 63, t3 = (b >> 12) & 63;
        numt = __expf(__int_as_float(rt.x) + D1[t1] + D2[t2] + D3[t3]);
        lsum += numt;
    }

    for (int off = 32; off > 0; off >>= 1)
        lsum += __shfl_down(lsum, off, 64);
    const int wave = tid >> 6, lane = tid & 63;
    if (lane == 0) red[wave] = lsum;
    __syncthreads();
    if (tid == 0) {
        float t = 0.f;
        for (int w = 0; w < 16; w++) t += red[w];
        s_inv = 1.f / t;
    }
    __syncthreads();
    const float inv = s_inv;

    float* orow = out + (size_t)s * NPATH;
#pragma unroll
    for (int i = 0; i < NFULL; i++)
        orow[tid + PBLK * i] = nums[i] * inv;
    if (tail)
        orow[NFULL * PBLK + tid] = numt * inv;
}

// ---------------------------------------------------------------------------
extern "C" void kernel_launch(void* const* d_in, const int* in_sizes, int n_in,
                              void* d_out, int out_size, void* d_ws, size_t ws_size,
                              hipStream_t stream) {
    const int*   resp  = (const int*)d_in[0];
    // d_in[1] (paths) intentionally unused: decoded analytically from index.
    const float* w_ss  = (const float*)d_in[2];
    const float* w_sp  = (const float*)d_in[3];
    const float* w_tr  = (const float*)d_in[4];
    float* out = (float*)d_out;

    int2* rec = (int2*)d_ws;   // NPATH records (8 B each)

    path_kernel<<<(NPATH + 255) / 256, 256, 0, stream>>>(w_sp, w_tr, rec);
    post_kernel<<<NSUB, PBLK, 0, stream>>>(resp, w_ss, rec, out);
}